// Round 6
// baseline (221.046 us; speedup 1.0000x reference)
//
#include <hip/hip_runtime.h>
#include <math.h>

// Problem constants
#define B_   128
#define K_   4
#define HW_  65536              // 256*256

constexpr int BLOCK = 256;
constexpr int NC    = 8;                    // chunks per (b,k) plane
constexpr int CHUNK = HW_ / NC;             // 8192 floats
constexpr int G     = CHUNK / 4 / BLOCK;    // 8 float4-groups per thread

// Native clang vector type (float4 struct is rejected by some builtins and
// codegens worse).
typedef float vfloat4 __attribute__((ext_vector_type(4)));

// Per-element math (t is exactly 0.0 or 1.0):
//   s   = sigmoid(x)
//   pt  = t*s + (1-t)*(1-s) = fma(t, 1-2s, s)   (true-class probability)
//   bce = -ln(pt); exp(-bce) == pt
//   focal += ALPHA * (1-pt)^2 * bce
// Native v_exp/v_rcp/v_log — rel err ~1e-6, threshold is 0.11.
__device__ __forceinline__ void proc_elem(float x, float t,
                                          float& fs, float& in, float& ps,
                                          float& i2, float& ms) {
    float e   = __expf(-fabsf(x));                 // e^{-|x|}
    float inv = __builtin_amdgcn_rcpf(1.0f + e);   // sigmoid(|x|)
    bool  pos = (x >= 0.0f);
    float s   = pos ? inv : 1.0f - inv;            // sigmoid(x)
    float nms = fmaf(-2.0f, s, 1.0f);              // 1 - 2s
    float pt  = fmaf(t, nms, s);                   // prob of true class
    float l   = __logf(pt);                        // ln(pt) = -bce
    float om  = 1.0f - pt;
    fs = fmaf(om * om * l, -0.8f, fs);             // += ALPHA*(1-pt)^2*bce
    float pc  = fminf(fmaxf(s, 1e-4f), 0.9999f);   // clip(sigmoid) -> v_med3
    ps += pc;
    in  = fmaf(pc, t, in);
    float m = pos ? 1.0f : 0.0f;                   // mask (x >= 0)
    ms += m;
    i2  = fmaf(m, t, i2);
}

__device__ __forceinline__ void proc4(const vfloat4& xv, const vfloat4& tv,
                                      float& fs, float& in, float& ps,
                                      float& i2, float& ms, float& ts) {
    proc_elem(xv.x, tv.x, fs, in, ps, i2, ms);
    proc_elem(xv.y, tv.y, fs, in, ps, i2, ms);
    proc_elem(xv.z, tv.z, fs, in, ps, i2, ms);
    proc_elem(xv.w, tv.w, fs, in, ps, i2, ms);
    ts += tv.x + tv.y + tv.z + tv.w;
}

// Split-K: one block per (b, chunk, k). Only 6 accumulators + 2-deep rotating
// load pipeline (A/B) => ~40 VGPRs, so launch_bounds(256,8) gives a REAL
// 32 waves/CU with zero spill risk. '#pragma unroll 1' prevents the compiler
// from unrolling-under-register-cap (the suspected R3 pathology). Steady
// state keeps one full group (t+x, 2 KB/wave) in flight during each group's
// compute: 32 waves * 2 KB = 64 KB/CU outstanding >> ~12 KB Little's-law
// requirement for 6.3 TB/s. Plain loads (no nt): targets are re-read by the
// 4 k-blocks and should hit L3.
__global__ __launch_bounds__(BLOCK, 8) void partial_kernel(
    const float* __restrict__ pred_masks,   // B*K*HW
    const float* __restrict__ targets,      // B*HW
    float* __restrict__ fsum,               // B*K
    float* __restrict__ inter,              // B*K
    float* __restrict__ psum,               // B*K
    float* __restrict__ i2s,                // B*K
    float* __restrict__ msum,               // B*K
    float* __restrict__ tsum)               // B  (accumulated K_ times)
{
    const int blk = blockIdx.x;             // ((b*NC + c)*K_ + k)
    const int k   = blk & (K_ - 1);
    const int bc  = blk >> 2;
    const int c   = bc & (NC - 1);
    const int b   = bc >> 3;                // NC == 8

    const vfloat4* __restrict__ t4 =
        reinterpret_cast<const vfloat4*>(targets + (size_t)b * HW_ + c * CHUNK);
    const vfloat4* __restrict__ x4 =
        reinterpret_cast<const vfloat4*>(pred_masks +
            ((size_t)(b * K_ + k)) * HW_ + c * CHUNK);

    float fs = 0.f, in = 0.f, ps = 0.f, i2 = 0.f, ms = 0.f, ts = 0.f;

    int idx = threadIdx.x;
    // Preload groups 0 (A) and 1 (B).
    vfloat4 tA = t4[idx];
    vfloat4 xA = x4[idx];
    vfloat4 tB = t4[idx + BLOCK];
    vfloat4 xB = x4[idx + BLOCK];

    // Rotating 2-stage pipeline: compute A, refill A from g+2; compute B,
    // refill B from g+3. While computing one group, the other's loads are
    // in flight.
    #pragma unroll 1
    for (int g = 0; g < G - 2; g += 2) {
        proc4(xA, tA, fs, in, ps, i2, ms, ts);
        tA = t4[idx + 2 * BLOCK];
        xA = x4[idx + 2 * BLOCK];
        proc4(xB, tB, fs, in, ps, i2, ms, ts);
        tB = t4[idx + 3 * BLOCK];
        xB = x4[idx + 3 * BLOCK];
        idx += 2 * BLOCK;
    }
    proc4(xA, tA, fs, in, ps, i2, ms, ts);
    proc4(xB, tB, fs, in, ps, i2, ms, ts);

    // Reduce 6 partials: wave shuffle (64 lanes) -> LDS across 4 waves -> atomic.
    float vals[6] = {fs, in, ps, i2, ms, ts};
    const int lane = threadIdx.x & 63;
    const int wave = threadIdx.x >> 6;

    #pragma unroll
    for (int v = 0; v < 6; ++v) {
        float x = vals[v];
        #pragma unroll
        for (int off = 32; off > 0; off >>= 1) x += __shfl_down(x, off, 64);
        vals[v] = x;
    }

    __shared__ float smem[6 * 4];
    if (lane == 0) {
        #pragma unroll
        for (int v = 0; v < 6; ++v) smem[v * 4 + wave] = vals[v];
    }
    __syncthreads();

    if (threadIdx.x < 6) {
        const int v = threadIdx.x;
        const float x = smem[v * 4 + 0] + smem[v * 4 + 1] +
                        smem[v * 4 + 2] + smem[v * 4 + 3];
        const int bk = b * K_ + k;
        float* dst;
        if      (v == 0) dst = &fsum[bk];
        else if (v == 1) dst = &inter[bk];
        else if (v == 2) dst = &psum[bk];
        else if (v == 3) dst = &i2s[bk];
        else if (v == 4) dst = &msum[bk];
        else             dst = &tsum[b];    // summed by all K_ k-blocks
        atomicAdd(dst, x);
    }
}

__global__ __launch_bounds__(128) void finalize_kernel(
    const float* __restrict__ pred_ious,    // B*K
    const float* __restrict__ fsum,
    const float* __restrict__ inter,
    const float* __restrict__ psum,
    const float* __restrict__ i2s,
    const float* __restrict__ msum,
    const float* __restrict__ tsum,
    float* __restrict__ out)                // [focal, dice, iou]
{
    const float lo[K_] = {0.00f, 0.01f, 0.09f, 0.25f};
    const float hi[K_] = {0.04f, 0.16f, 0.49f, 1.00f};
    const float SMOOTH = 0.0001f;

    const int b = threadIdx.x;              // 128 threads, one per sample
    const float ts = tsum[b] * 0.25f;       // undo K_-fold accumulation
    const float ratio = ts * (1.0f / (float)HW_);

    float cnt = 0.f, fA = 0.f, dA = 0.f, iA = 0.f;
    #pragma unroll
    for (int k = 0; k < K_; ++k) {
        const bool valid = (ratio > lo[k]) && (ratio < hi[k]);
        if (valid) {
            cnt += 1.0f;
            fA += fsum[b * K_ + k] * (1.0f / (float)HW_);
            const float in_ = inter[b * K_ + k];
            const float ps_ = psum[b * K_ + k];
            dA += 1.0f - (2.0f * in_ + SMOOTH) / (ps_ + ts + SMOOTH);
            const float i2_ = i2s[b * K_ + k];
            const float ms_ = msum[b * K_ + k];
            const float gt  = (i2_ + SMOOTH) / (ms_ + ts - i2_ + SMOOTH);
            const float d   = pred_ious[b * K_ + k] - gt;
            iA += d * d;
        }
    }
    const float invc = (cnt > 0.f) ? (1.0f / cnt) : 0.0f;
    fA *= invc; dA *= invc; iA *= invc;      // per_sample (0 when cnt==0)
    float vb = (cnt > 0.f) ? 1.0f : 0.0f;

    // Reduce 4 quantities across 128 threads (2 waves).
    float vals[4] = {fA, dA, iA, vb};
    const int lane = threadIdx.x & 63;
    const int wave = threadIdx.x >> 6;
    #pragma unroll
    for (int v = 0; v < 4; ++v) {
        float x = vals[v];
        #pragma unroll
        for (int off = 32; off > 0; off >>= 1) x += __shfl_down(x, off, 64);
        vals[v] = x;
    }
    __shared__ float smem[4 * 2];
    if (lane == 0) {
        #pragma unroll
        for (int v = 0; v < 4; ++v) smem[v * 2 + wave] = vals[v];
    }
    __syncthreads();
    if (threadIdx.x == 0) {
        const float fT  = smem[0] + smem[1];
        const float dT  = smem[2] + smem[3];
        const float iT  = smem[4] + smem[5];
        const float vbT = smem[6] + smem[7];
        const float scale = (vbT > 0.f) ? (1.0f / vbT) : 1.0f;
        out[0] = 20.0f * fT * scale;   // FOCAL_W
        out[1] = dT * scale;           // DICE_W
        out[2] = iT * scale;           // IOU_W
    }
}

extern "C" void kernel_launch(void* const* d_in, const int* in_sizes, int n_in,
                              void* d_out, int out_size, void* d_ws, size_t ws_size,
                              hipStream_t stream) {
    const float* pred_masks = (const float*)d_in[0];   // B*K*HW
    const float* pred_ious  = (const float*)d_in[1];   // B*K
    const float* targets    = (const float*)d_in[2];   // B*HW
    float* out = (float*)d_out;

    float* ws    = (float*)d_ws;
    float* fsum  = ws;            // B*K = 512
    float* inter = ws + 512;
    float* psum  = ws + 1024;
    float* i2s   = ws + 1536;
    float* msum  = ws + 2048;
    float* tsum  = ws + 2560;     // B = 128  -> total 2688 floats

    (void)hipMemsetAsync(d_ws, 0, 2688 * sizeof(float), stream);

    partial_kernel<<<B_ * NC * K_, BLOCK, 0, stream>>>(
        pred_masks, targets, fsum, inter, psum, i2s, msum, tsum);
    finalize_kernel<<<1, 128, 0, stream>>>(
        pred_ious, fsum, inter, psum, i2s, msum, tsum, out);
}